// Round 11
// baseline (1381.659 us; speedup 1.0000x reference)
//
#include <hip/hip_runtime.h>
#include <cstddef>

// ---- problem constants ----
#define NN     50000
#define NE     800000
#define IND    128
#define EMBD   64
#define IN1    192     // IND + EMBD
#define HDIM   256
#define RR     12
#define BB     8
#define NGENE  20000
#define NPATH  2000
#define NRK    (RR * NN)               // 600000 segment keys
#define SCB    1024
#define NSB    ((NRK + SCB - 1) / SCB) // 586

typedef __attribute__((ext_vector_type(8))) short short8;
typedef __attribute__((ext_vector_type(4))) float f32x4;
typedef unsigned short ushortT;
typedef __attribute__((address_space(3))) void lds_void;
typedef __attribute__((address_space(1))) const void glb_void;

__device__ __forceinline__ float bu2f(unsigned short u) {
  unsigned int x = ((unsigned int)u) << 16;
  return __builtin_bit_cast(float, x);
}
__device__ __forceinline__ unsigned short f2bu(float f) {
  unsigned int x = __builtin_bit_cast(unsigned int, f);
  unsigned int r = (x + 0x7fffu + ((x >> 16) & 1u)) >> 16;
  return (unsigned short)r;
}

// Global A-layout swizzle: within each 64-elem k-group, 8-elem chunk ch of row g
// is stored at chunk position ch ^ (g & 7). GEMM DMA-stages raw row slices, so the
// LDS tile arrives pre-swizzled (conflict-free ds_read_b128 frag loads).

// ---------- build x0 = [x | 0] bf16, swizzled ----------
__global__ void k_build_x0(const float* __restrict__ x, ushortT* __restrict__ x0) {
  int t = blockIdx.x * 256 + threadIdx.x;
  if (t >= NN * IN1) return;
  int n = t / IN1, i = t - n * IN1;
  float v = (i < IND) ? x[(size_t)n * IND + i] : 0.0f;
  int kt = i >> 6, ch = (i >> 3) & 7, off = i & 7;
  x0[(size_t)n * IN1 + kt * 64 + ((ch ^ (n & 7)) * 8) + off] = f2bu(v);
}

__global__ void k_add_emb(const int* __restrict__ idx, const float* __restrict__ emb,
                          ushortT* __restrict__ x0, int count) {
  int t = blockIdx.x * 256 + threadIdx.x;
  if (t >= count * EMBD) return;
  int g = t / EMBD, j = t - g * EMBD;
  int n = idx[g];
  int ch = (j >> 3) & 7, off = j & 7;
  x0[(size_t)n * IN1 + 128 + ((ch ^ (n & 7)) * 8) + off] = f2bu(emb[t]);
}

// ---------- per-(rel,dst) edge counts ----------
__global__ void k_count(const int* __restrict__ ei, const int* __restrict__ et,
                        int* __restrict__ cnt) {
  int e = blockIdx.x * 256 + threadIdx.x;
  if (e >= NE) return;
  atomicAdd(&cnt[et[e] * NN + ei[NE + e]], 1);
}

// ---------- 3-kernel exclusive scan ----------
__global__ __launch_bounds__(256) void k_scan1(const int* __restrict__ cnt,
                                               int* __restrict__ bsum) {
  __shared__ int lds[256];
  int t = threadIdx.x;
  int base = blockIdx.x * SCB + t * 4;
  int s = 0;
#pragma unroll
  for (int j = 0; j < 4; j++) { int idx = base + j; if (idx < NRK) s += cnt[idx]; }
  lds[t] = s; __syncthreads();
  for (int d = 128; d > 0; d >>= 1) { if (t < d) lds[t] += lds[t + d]; __syncthreads(); }
  if (t == 0) bsum[blockIdx.x] = lds[0];
}

__global__ __launch_bounds__(1024) void k_scan2(const int* __restrict__ bsum,
                                                int* __restrict__ bscan) {
  __shared__ int lds[1024];
  int t = threadIdx.x;
  int v = (t < NSB) ? bsum[t] : 0;
  lds[t] = v; __syncthreads();
  for (int d = 1; d < 1024; d <<= 1) {
    int add = (t >= d) ? lds[t - d] : 0; __syncthreads();
    lds[t] += add; __syncthreads();
  }
  if (t < NSB) bscan[t] = lds[t] - v;
}

__global__ __launch_bounds__(256) void k_scan3(const int* __restrict__ cnt,
                                               const int* __restrict__ bscan,
                                               int* __restrict__ off) {
  __shared__ int lds[256];
  int t = threadIdx.x;
  int base = blockIdx.x * SCB + t * 4;
  int v[4]; int s = 0;
#pragma unroll
  for (int j = 0; j < 4; j++) { int idx = base + j; v[j] = (idx < NRK) ? cnt[idx] : 0; s += v[j]; }
  lds[t] = s; __syncthreads();
  for (int d = 1; d < 256; d <<= 1) {
    int add = (t >= d) ? lds[t - d] : 0; __syncthreads();
    lds[t] += add; __syncthreads();
  }
  int ex = lds[t] - s + bscan[blockIdx.x];
#pragma unroll
  for (int j = 0; j < 4; j++) {
    int idx = base + j;
    if (idx < NRK) { off[idx] = ex; ex += v[j]; }
  }
}

__global__ void k_fill(const int* __restrict__ ei, const int* __restrict__ et,
                       const int* __restrict__ off, int* __restrict__ fill,
                       int* __restrict__ srcs) {
  int e = blockIdx.x * 256 + threadIdx.x;
  if (e >= NE) return;
  int key = et[e] * NN + ei[NE + e];
  int pos = off[key] + atomicAdd(&fill[key], 1);
  srcs[pos] = ei[e];
}

// ---------- W[r][o][i] = bf16( sum_b comp[r,b]*basis[b,i,o] ) (linear layout) ----------
__global__ void k_wcat(const float* __restrict__ comp, const float* __restrict__ basis,
                       ushortT* __restrict__ W, int in_dim) {
  int t = blockIdx.x * 256 + threadIdx.x;
  int total = RR * HDIM * in_dim;
  if (t >= total) return;
  int i = t % in_dim;
  int o = (t / in_dim) & 255;
  int r = t / (in_dim * 256);
  float acc = 0.f;
#pragma unroll
  for (int b = 0; b < BB; b++)
    acc += comp[r * BB + b] * basis[((size_t)b * in_dim + i) * HDIM + o];
  W[t] = f2bu(acc);
}

__global__ void k_troot(const float* __restrict__ root, ushortT* __restrict__ rt,
                        int in_dim) {
  int t = blockIdx.x * 256 + threadIdx.x;
  if (t >= in_dim * HDIM) return;
  int i = t % in_dim, o = t / in_dim;
  rt[t] = f2bu(root[(size_t)i * HDIM + o]);
}

// ---------- CSR gather aggregation: one wave per (dst, rl) ----------
// xin is row-swizzled (key src&7): un-swizzle on read; aggB written swizzled (key dst&7).
__global__ __launch_bounds__(256) void k_agg(const int* __restrict__ srcs,
                                             const int* __restrict__ off,
                                             const int* __restrict__ cnt,
                                             const ushortT* __restrict__ xin,
                                             ushortT* __restrict__ aggB,
                                             int in_dim, int r0) {
  int wave = (blockIdx.x * 256 + threadIdx.x) >> 6;
  int lane = threadIdx.x & 63;
  int dst = wave >> 2;
  int rl  = wave & 3;
  if (dst >= NN) return;
  int key = (r0 + rl) * NN + dst;
  int beg = off[key];
  int n   = cnt[key];
  bool act = lane * 4 < in_dim;
  int kt = lane >> 4, chl = (lane >> 1) & 7, offh = (lane & 1) * 4;
  int kbase = kt * 64 + offh;
  float a0 = 0.f, a1 = 0.f, a2 = 0.f, a3 = 0.f;
  int p = 0;
  for (; p + 2 <= n; p += 2) {
    int sa = srcs[beg + p];
    int sb = srcs[beg + p + 1];
    if (act) {
      ushort4 va = *(const ushort4*)(xin + (size_t)sa * in_dim + kbase + ((chl ^ (sa & 7)) * 8));
      ushort4 vb = *(const ushort4*)(xin + (size_t)sb * in_dim + kbase + ((chl ^ (sb & 7)) * 8));
      a0 += bu2f(va.x); a1 += bu2f(va.y); a2 += bu2f(va.z); a3 += bu2f(va.w);
      a0 += bu2f(vb.x); a1 += bu2f(vb.y); a2 += bu2f(vb.z); a3 += bu2f(vb.w);
    }
  }
  if (p < n) {
    int sa = srcs[beg + p];
    if (act) {
      ushort4 va = *(const ushort4*)(xin + (size_t)sa * in_dim + kbase + ((chl ^ (sa & 7)) * 8));
      a0 += bu2f(va.x); a1 += bu2f(va.y); a2 += bu2f(va.z); a3 += bu2f(va.w);
    }
  }
  if (act) {
    float s = 1.0f / (float)max(n, 1);
    ushort4 o;
    o.x = f2bu(a0 * s); o.y = f2bu(a1 * s); o.z = f2bu(a2 * s); o.w = f2bu(a3 * s);
    *(ushort4*)(aggB + ((size_t)dst * 4 + rl) * in_dim + kbase + ((chl ^ (dst & 7)) * 8)) = o;
  }
}

// ---------- multi-segment MFMA GEMM, 64x128 tile, global_load_lds staging ----------
// grid (2, 782): bn = blockIdx.x*128, bm = blockIdx.y*64; 4 waves (wr 0..1 x wc 0..1).
// 1564 blocks -> ~6 blocks/CU = 24 waves/CU for latency hiding.
// A sources globally swizzled -> DMA'd LDS tile pre-swizzled -> conflict-free frag reads.
// mode 0: C = acc + bias (seg0 = xin); mode 1: C += acc (all segs aggB).
__global__ __launch_bounds__(256, 4) void k_gemm(const ushortT* __restrict__ xin,
                                                 const ushortT* __restrict__ aggB,
                                                 const ushortT* __restrict__ Wchunk,
                                                 float* __restrict__ C,
                                                 const float* __restrict__ bias,
                                                 int in_dim, int nseg, int mode) {
  __shared__ ushortT As[2][64 * 64];
  const int tid = threadIdx.x;
  const int bn = blockIdx.x * 128;
  const int bm = blockIdx.y * 64;
  const int wv = tid >> 6, l = tid & 63;
  const int wr = wv >> 1, wc = wv & 1;
  const int lm = l & 15, lq = l >> 4;
  const int lrow = l >> 3, lch = l & 7;   // staging: lane covers row +lrow, chunk lch
  const int nkt = in_dim >> 6;
  const int first = (mode == 0) ? 1 : 0;
  const int totKt = nseg * nkt;

  f32x4 acc[2][4];
#pragma unroll
  for (int mt = 0; mt < 2; mt++)
#pragma unroll
    for (int nt = 0; nt < 4; nt++) acc[mt][nt] = (f32x4){0.f, 0.f, 0.f, 0.f};

  auto stage = [&](int buf, int seg, int kt) {
    const ushortT* ab; size_t str;
    if (first && seg == 0) { ab = xin; str = (size_t)in_dim; }
    else { ab = aggB + (size_t)(seg - first) * in_dim; str = (size_t)4 * in_dim; }
#pragma unroll
    for (int j = 0; j < 2; j++) {
      int r = j * 32 + wv * 8;                 // wave-uniform LDS row base
      int g = bm + r + lrow; if (g >= NN) g = NN - 1;
      const ushortT* gp = ab + (size_t)g * str + kt * 64 + lch * 8;
      ushortT* lp = &As[buf][r * 64];
      __builtin_amdgcn_global_load_lds((glb_void*)gp, (lds_void*)lp, 16, 0, 0);
    }
  };

  auto mfmaTile = [&](int buf, int segC, int ktC) {
    short8 bf[2][4];
    const ushortT* wt = Wchunk + (size_t)(bn + wc * 64 + lm) * in_dim +
                        (size_t)segC * 256 * in_dim + ktC * 64 + lq * 8;
#pragma unroll
    for (int nt = 0; nt < 4; nt++) {
      bf[0][nt] = *(const short8*)(wt + (size_t)nt * 16 * in_dim);
      bf[1][nt] = *(const short8*)(wt + (size_t)nt * 16 * in_dim + 32);
    }
#pragma unroll
    for (int ks = 0; ks < 2; ks++) {
      short8 af[2];
#pragma unroll
      for (int mt = 0; mt < 2; mt++) {
        int ar = wr * 32 + mt * 16 + lm;
        af[mt] = *(const short8*)(&As[buf][ar * 64 + (((ks * 4) + lq) ^ (ar & 7)) * 8]);
      }
#pragma unroll
      for (int mt = 0; mt < 2; mt++)
#pragma unroll
        for (int nt = 0; nt < 4; nt++)
          acc[mt][nt] = __builtin_amdgcn_mfma_f32_16x16x32_bf16(af[mt], bf[ks][nt],
                                                                acc[mt][nt], 0, 0, 0);
    }
  };

  int segL = 0, ktL = 0, segP = 0, ktP = 0;
  auto bump = [&](int& s, int& k) { if (++k == nkt) { k = 0; s++; } };

  stage(0, 0, 0);
  __syncthreads();
  for (int t = 0; t < totKt; t++) {
    if (t + 1 < totKt) { bump(segP, ktP); stage((t + 1) & 1, segP, ktP); }
    mfmaTile(t & 1, segL, ktL);
    bump(segL, ktL);
    __syncthreads();
  }

  // ---- epilogue: through-LDS coalesced fp32 C write, 2 slices of 32 rows ----
  float* Asf = (float*)As;
  for (int s = 0; s < 2; s++) {
    __syncthreads();
    if (wr == s) {
#pragma unroll
      for (int mt = 0; mt < 2; mt++)
#pragma unroll
        for (int r = 0; r < 4; r++)
#pragma unroll
          for (int nt = 0; nt < 4; nt++)
            Asf[(mt * 16 + lq * 4 + r) * 128 + wc * 64 + nt * 16 + lm] = acc[mt][nt][r];
    }
    __syncthreads();
#pragma unroll
    for (int j = 0; j < 4; j++) {
      int f = j * 256 + tid;          // float4 index 0..1023
      int row = f >> 5, c4 = (f & 31) * 4;
      int grow = bm + s * 32 + row;
      if (grow < NN) {
        float4 v = *(float4*)(&Asf[row * 128 + c4]);
        float* cp = C + (size_t)grow * HDIM + bn + c4;
        if (mode == 1) {
          float4 o = *(float4*)cp;
          v.x += o.x; v.y += o.y; v.z += o.z; v.w += o.w;
        } else {
          v.x += bias[bn + c4]; v.y += bias[bn + c4 + 1];
          v.z += bias[bn + c4 + 2]; v.w += bias[bn + c4 + 3];
        }
        *(float4*)cp = v;
      }
    }
  }
}

// ---------- head-softmax attention: fp32 in, bf16 out (swizzled rows) ----------
__global__ void k_attn(const float* __restrict__ h, const float* __restrict__ att,
                       ushortT* __restrict__ hb) {
  int gtid = blockIdx.x * 256 + threadIdx.x;
  int node = gtid >> 6;
  int lane = gtid & 63;
  if (node >= NN) return;
  const float* hp = h + (size_t)node * HDIM;
  float v[4], s[4];
#pragma unroll
  for (int hd = 0; hd < 4; hd++) {
    v[hd] = hp[hd * 64 + lane];
    s[hd] = v[hd] * att[hd * 64 + lane];
  }
#pragma unroll
  for (int off = 32; off > 0; off >>= 1) {
#pragma unroll
    for (int hd = 0; hd < 4; hd++) s[hd] += __shfl_xor(s[hd], off, 64);
  }
  float mx = fmaxf(fmaxf(s[0], s[1]), fmaxf(s[2], s[3]));
  float ex[4], sum = 0.f;
#pragma unroll
  for (int hd = 0; hd < 4; hd++) { ex[hd] = __expf(s[hd] - mx); sum += ex[hd]; }
  float inv = 1.0f / sum;
  ushortT* ob = hb + (size_t)node * HDIM;
  int swz = (((lane >> 3) ^ (node & 7)) * 8) + (lane & 7);
#pragma unroll
  for (int hd = 0; hd < 4; hd++) ob[hd * 64 + swz] = f2bu(v[hd] * (ex[hd] * inv));
}

// ---------- prediction head: h is swizzled; un-swizzle on read ----------
__global__ void k_pred(const ushortT* __restrict__ h, const float* __restrict__ w,
                       const float* __restrict__ b, float* __restrict__ out) {
  int t = blockIdx.x * 256 + threadIdx.x;
  if (t >= NN * 12) return;
  int n = t / 12, j = t - n * 12;
  float acc = b[j];
  const ushortT* hp = h + (size_t)n * HDIM;
  int key = n & 7;
#pragma unroll
  for (int kt = 0; kt < 4; kt++)
#pragma unroll
    for (int cs = 0; cs < 8; cs++) {
      int ch = cs ^ key;                 // logical chunk for stored chunk cs
      int kb = kt * 64 + ch * 8;
      const ushortT* hh = hp + kt * 64 + cs * 8;
#pragma unroll
      for (int o = 0; o < 8; o++) acc += bu2f(hh[o]) * w[(kb + o) * 12 + j];
    }
  out[t] = acc;
}

extern "C" void kernel_launch(void* const* d_in, const int* in_sizes, int n_in,
                              void* d_out, int out_size, void* d_ws, size_t ws_size,
                              hipStream_t stream) {
  const float* x         = (const float*)d_in[0];
  const int*   edge_idx  = (const int*)d_in[1];
  const int*   edge_type = (const int*)d_in[2];
  const int*   gene_idx  = (const int*)d_in[3];
  const int*   path_idx  = (const int*)d_in[4];
  const float* gene_emb  = (const float*)d_in[5];
  const float* path_emb  = (const float*)d_in[6];
  const float* comp1     = (const float*)d_in[7];
  const float* basis1    = (const float*)d_in[8];
  const float* root1     = (const float*)d_in[9];
  const float* bias1     = (const float*)d_in[10];
  const float* att1      = (const float*)d_in[11];
  const float* comp2     = (const float*)d_in[12];
  const float* basis2    = (const float*)d_in[13];
  const float* root2     = (const float*)d_in[14];
  const float* bias2     = (const float*)d_in[15];
  const float* att2      = (const float*)d_in[16];
  const float* pred_w    = (const float*)d_in[17];
  const float* pred_b    = (const float*)d_in[18];
  float* out = (float*)d_out;

  // workspace layout (bytes, 16B aligned); total ~218 MB (252 MB proven safe)
  char* ws = (char*)d_ws;
  float*   C     = (float*)(ws);                     // 50048*256*4 = 51,249,152
  ushortT* x0b   = (ushortT*)(ws + 51249152);        // 19.2 MB (h2b overlays later)
  ushortT* h2b   = (ushortT*)(ws + 51249152);        // 25.6 MB (x0b dead by then)
  ushortT* h1b   = (ushortT*)(ws + 76849152);        // 25,600,000
  ushortT* aggB  = (ushortT*)(ws + 102449152);       // 50000*4*256*2 = 102,400,000
  ushortT* Wall1 = (ushortT*)(ws + 204849152);       // 13*256*192*2 = 1,277,952
  ushortT* Wall2 = (ushortT*)(ws + 206127104);       // 13*256*256*2 = 1,703,936
  int*     cnt   = (int*)(ws + 207831040);           // 2,400,000
  int*     off   = (int*)(ws + 210231040);           // 2,400,000
  int*     srcs  = (int*)(ws + 212631040);           // 3,200,000
  int*     fill  = (int*)(ws + 215831040);           // 2,400,000
  int*     bsum  = (int*)(ws + 218231040);           // 4 KB
  int*     bscan = (int*)(ws + 218235136);           // 4 KB

  dim3 blk(256);

  // ---- stage 0: features + CSR build + weight prep ----
  k_build_x0<<<dim3((NN * IN1) / 256), blk, 0, stream>>>(x, x0b);
  k_add_emb<<<dim3((NGENE * EMBD) / 256), blk, 0, stream>>>(gene_idx, gene_emb, x0b, NGENE);
  k_add_emb<<<dim3((NPATH * EMBD) / 256), blk, 0, stream>>>(path_idx, path_emb, x0b, NPATH);
  hipMemsetAsync(cnt, 0, NRK * 4, stream);
  hipMemsetAsync(fill, 0, NRK * 4, stream);
  k_count<<<dim3(NE / 256), blk, 0, stream>>>(edge_idx, edge_type, cnt);
  k_scan1<<<dim3(NSB), blk, 0, stream>>>(cnt, bsum);
  k_scan2<<<dim3(1), dim3(1024), 0, stream>>>(bsum, bscan);
  k_scan3<<<dim3(NSB), blk, 0, stream>>>(cnt, bscan, off);
  k_fill<<<dim3(NE / 256), blk, 0, stream>>>(edge_idx, edge_type, off, fill, srcs);
  k_troot<<<dim3((IN1 * HDIM) / 256), blk, 0, stream>>>(root1, Wall1, IN1);
  k_troot<<<dim3((HDIM * HDIM) / 256), blk, 0, stream>>>(root2, Wall2, HDIM);
  k_wcat<<<dim3((RR * HDIM * IN1) / 256), blk, 0, stream>>>(comp1, basis1, Wall1 + 256 * IN1, IN1);
  k_wcat<<<dim3((RR * HDIM * HDIM) / 256), blk, 0, stream>>>(comp2, basis2, Wall2 + 256 * HDIM, HDIM);

  dim3 agrid(NN), gblk(256), ggrid(2, 782);
  dim3 ngrid((NN * 64 + 255) / 256);

  // ---- conv1: chunks {root+r0-3}, {r4-7}, {r8-11}, then attention ----
  k_agg<<<agrid, blk, 0, stream>>>(srcs, off, cnt, x0b, aggB, IN1, 0);
  k_gemm<<<ggrid, gblk, 0, stream>>>(x0b, aggB, Wall1, C, bias1, IN1, 5, 0);
  k_agg<<<agrid, blk, 0, stream>>>(srcs, off, cnt, x0b, aggB, IN1, 4);
  k_gemm<<<ggrid, gblk, 0, stream>>>(x0b, aggB, Wall1 + (size_t)5 * 256 * IN1, C, bias1, IN1, 4, 1);
  k_agg<<<agrid, blk, 0, stream>>>(srcs, off, cnt, x0b, aggB, IN1, 8);
  k_gemm<<<ggrid, gblk, 0, stream>>>(x0b, aggB, Wall1 + (size_t)9 * 256 * IN1, C, bias1, IN1, 4, 1);
  k_attn<<<ngrid, blk, 0, stream>>>(C, att1, h1b);

  // ---- conv2 ----
  k_agg<<<agrid, blk, 0, stream>>>(srcs, off, cnt, h1b, aggB, HDIM, 0);
  k_gemm<<<ggrid, gblk, 0, stream>>>(h1b, aggB, Wall2, C, bias2, HDIM, 5, 0);
  k_agg<<<agrid, blk, 0, stream>>>(srcs, off, cnt, h1b, aggB, HDIM, 4);
  k_gemm<<<ggrid, gblk, 0, stream>>>(h1b, aggB, Wall2 + (size_t)5 * 256 * HDIM, C, bias2, HDIM, 4, 1);
  k_agg<<<agrid, blk, 0, stream>>>(srcs, off, cnt, h1b, aggB, HDIM, 8);
  k_gemm<<<ggrid, gblk, 0, stream>>>(h1b, aggB, Wall2 + (size_t)9 * 256 * HDIM, C, bias2, HDIM, 4, 1);
  k_attn<<<ngrid, blk, 0, stream>>>(C, att2, h2b);

  // ---- prediction head ----
  k_pred<<<dim3((NN * 12 + 255) / 256), blk, 0, stream>>>(h2b, pred_w, pred_b, out);
}

// Round 12
// 1039.184 us; speedup vs baseline: 1.3296x; 1.3296x over previous
//
#include <hip/hip_runtime.h>
#include <cstddef>

// ---- problem constants ----
#define NN     50000
#define NE     800000
#define IND    128
#define EMBD   64
#define IN1    192     // IND + EMBD
#define HDIM   256
#define RR     12
#define BB     8
#define NGENE  20000
#define NPATH  2000
#define NRK    (RR * NN)               // 600000 segment keys
#define SCB    1024
#define NSB    ((NRK + SCB - 1) / SCB) // 586

typedef __attribute__((ext_vector_type(8))) short short8;
typedef __attribute__((ext_vector_type(4))) float f32x4;
typedef unsigned short ushortT;
typedef __attribute__((address_space(3))) void lds_void;
typedef __attribute__((address_space(1))) const void glb_void;

__device__ __forceinline__ float bu2f(unsigned short u) {
  unsigned int x = ((unsigned int)u) << 16;
  return __builtin_bit_cast(float, x);
}
__device__ __forceinline__ unsigned short f2bu(float f) {
  unsigned int x = __builtin_bit_cast(unsigned int, f);
  unsigned int r = (x + 0x7fffu + ((x >> 16) & 1u)) >> 16;
  return (unsigned short)r;
}

// Global A-layout swizzle: within each 64-elem k-group, 8-elem chunk ch of row g
// is stored at chunk position ch ^ (g & 7). GEMM DMA-stages raw row slices, so the
// LDS tile arrives pre-swizzled (conflict-free ds_read_b128 frag loads).

// ---------- build x0 = [x | 0] bf16, swizzled ----------
__global__ void k_build_x0(const float* __restrict__ x, ushortT* __restrict__ x0) {
  int t = blockIdx.x * 256 + threadIdx.x;
  if (t >= NN * IN1) return;
  int n = t / IN1, i = t - n * IN1;
  float v = (i < IND) ? x[(size_t)n * IND + i] : 0.0f;
  int kt = i >> 6, ch = (i >> 3) & 7, off = i & 7;
  x0[(size_t)n * IN1 + kt * 64 + ((ch ^ (n & 7)) * 8) + off] = f2bu(v);
}

__global__ void k_add_emb(const int* __restrict__ idx, const float* __restrict__ emb,
                          ushortT* __restrict__ x0, int count) {
  int t = blockIdx.x * 256 + threadIdx.x;
  if (t >= count * EMBD) return;
  int g = t / EMBD, j = t - g * EMBD;
  int n = idx[g];
  int ch = (j >> 3) & 7, off = j & 7;
  x0[(size_t)n * IN1 + 128 + ((ch ^ (n & 7)) * 8) + off] = f2bu(emb[t]);
}

// ---------- per-(rel,dst) edge counts ----------
__global__ void k_count(const int* __restrict__ ei, const int* __restrict__ et,
                        int* __restrict__ cnt) {
  int e = blockIdx.x * 256 + threadIdx.x;
  if (e >= NE) return;
  atomicAdd(&cnt[et[e] * NN + ei[NE + e]], 1);
}

// ---------- 3-kernel exclusive scan ----------
__global__ __launch_bounds__(256) void k_scan1(const int* __restrict__ cnt,
                                               int* __restrict__ bsum) {
  __shared__ int lds[256];
  int t = threadIdx.x;
  int base = blockIdx.x * SCB + t * 4;
  int s = 0;
#pragma unroll
  for (int j = 0; j < 4; j++) { int idx = base + j; if (idx < NRK) s += cnt[idx]; }
  lds[t] = s; __syncthreads();
  for (int d = 128; d > 0; d >>= 1) { if (t < d) lds[t] += lds[t + d]; __syncthreads(); }
  if (t == 0) bsum[blockIdx.x] = lds[0];
}

__global__ __launch_bounds__(1024) void k_scan2(const int* __restrict__ bsum,
                                                int* __restrict__ bscan) {
  __shared__ int lds[1024];
  int t = threadIdx.x;
  int v = (t < NSB) ? bsum[t] : 0;
  lds[t] = v; __syncthreads();
  for (int d = 1; d < 1024; d <<= 1) {
    int add = (t >= d) ? lds[t - d] : 0; __syncthreads();
    lds[t] += add; __syncthreads();
  }
  if (t < NSB) bscan[t] = lds[t] - v;
}

__global__ __launch_bounds__(256) void k_scan3(const int* __restrict__ cnt,
                                               const int* __restrict__ bscan,
                                               int* __restrict__ off) {
  __shared__ int lds[256];
  int t = threadIdx.x;
  int base = blockIdx.x * SCB + t * 4;
  int v[4]; int s = 0;
#pragma unroll
  for (int j = 0; j < 4; j++) { int idx = base + j; v[j] = (idx < NRK) ? cnt[idx] : 0; s += v[j]; }
  lds[t] = s; __syncthreads();
  for (int d = 1; d < 256; d <<= 1) {
    int add = (t >= d) ? lds[t - d] : 0; __syncthreads();
    lds[t] += add; __syncthreads();
  }
  int ex = lds[t] - s + bscan[blockIdx.x];
#pragma unroll
  for (int j = 0; j < 4; j++) {
    int idx = base + j;
    if (idx < NRK) { off[idx] = ex; ex += v[j]; }
  }
}

__global__ void k_fill(const int* __restrict__ ei, const int* __restrict__ et,
                       const int* __restrict__ off, int* __restrict__ fill,
                       int* __restrict__ srcs) {
  int e = blockIdx.x * 256 + threadIdx.x;
  if (e >= NE) return;
  int key = et[e] * NN + ei[NE + e];
  int pos = off[key] + atomicAdd(&fill[key], 1);
  srcs[pos] = ei[e];
}

// ---------- W[r][o][i] = bf16( sum_b comp[r,b]*basis[b,i,o] ) (linear layout) ----------
__global__ void k_wcat(const float* __restrict__ comp, const float* __restrict__ basis,
                       ushortT* __restrict__ W, int in_dim) {
  int t = blockIdx.x * 256 + threadIdx.x;
  int total = RR * HDIM * in_dim;
  if (t >= total) return;
  int i = t % in_dim;
  int o = (t / in_dim) & 255;
  int r = t / (in_dim * 256);
  float acc = 0.f;
#pragma unroll
  for (int b = 0; b < BB; b++)
    acc += comp[r * BB + b] * basis[((size_t)b * in_dim + i) * HDIM + o];
  W[t] = f2bu(acc);
}

__global__ void k_troot(const float* __restrict__ root, ushortT* __restrict__ rt,
                        int in_dim) {
  int t = blockIdx.x * 256 + threadIdx.x;
  if (t >= in_dim * HDIM) return;
  int i = t % in_dim, o = t / in_dim;
  rt[t] = f2bu(root[(size_t)i * HDIM + o]);
}

// ---------- CSR gather aggregation: one wave per (dst, rl) ----------
// xin is row-swizzled (key src&7): un-swizzle on read; aggB written swizzled (key dst&7).
__global__ __launch_bounds__(256) void k_agg(const int* __restrict__ srcs,
                                             const int* __restrict__ off,
                                             const int* __restrict__ cnt,
                                             const ushortT* __restrict__ xin,
                                             ushortT* __restrict__ aggB,
                                             int in_dim, int r0) {
  int wave = (blockIdx.x * 256 + threadIdx.x) >> 6;
  int lane = threadIdx.x & 63;
  int dst = wave >> 2;
  int rl  = wave & 3;
  if (dst >= NN) return;
  int key = (r0 + rl) * NN + dst;
  int beg = off[key];
  int n   = cnt[key];
  bool act = lane * 4 < in_dim;
  int kt = lane >> 4, chl = (lane >> 1) & 7, offh = (lane & 1) * 4;
  int kbase = kt * 64 + offh;
  float a0 = 0.f, a1 = 0.f, a2 = 0.f, a3 = 0.f;
  int p = 0;
  for (; p + 2 <= n; p += 2) {
    int sa = srcs[beg + p];
    int sb = srcs[beg + p + 1];
    if (act) {
      ushort4 va = *(const ushort4*)(xin + (size_t)sa * in_dim + kbase + ((chl ^ (sa & 7)) * 8));
      ushort4 vb = *(const ushort4*)(xin + (size_t)sb * in_dim + kbase + ((chl ^ (sb & 7)) * 8));
      a0 += bu2f(va.x); a1 += bu2f(va.y); a2 += bu2f(va.z); a3 += bu2f(va.w);
      a0 += bu2f(vb.x); a1 += bu2f(vb.y); a2 += bu2f(vb.z); a3 += bu2f(vb.w);
    }
  }
  if (p < n) {
    int sa = srcs[beg + p];
    if (act) {
      ushort4 va = *(const ushort4*)(xin + (size_t)sa * in_dim + kbase + ((chl ^ (sa & 7)) * 8));
      a0 += bu2f(va.x); a1 += bu2f(va.y); a2 += bu2f(va.z); a3 += bu2f(va.w);
    }
  }
  if (act) {
    float s = 1.0f / (float)max(n, 1);
    ushort4 o;
    o.x = f2bu(a0 * s); o.y = f2bu(a1 * s); o.z = f2bu(a2 * s); o.w = f2bu(a3 * s);
    *(ushort4*)(aggB + ((size_t)dst * 4 + rl) * in_dim + kbase + ((chl ^ (dst & 7)) * 8)) = o;
  }
}

// ---------- multi-segment MFMA GEMM, 128x256 tile (full width), DMA staging ----------
// grid (391): bm = blockIdx.x*128; 512 threads = 8 waves (wr=wv>>2 0..1, wc=wv&3 0..3).
// A staged once per tile serves all 256 output cols -> half the barrier cost per MFMA.
// mode 0: C = acc + bias (seg0 = xin)
// mode 1: C += acc
// mode 2: acc += C; fused 4-head softmax attention; swizzled bf16 h store
__global__ __launch_bounds__(512, 2) void k_gemm(const ushortT* __restrict__ xin,
                                                 const ushortT* __restrict__ aggB,
                                                 const ushortT* __restrict__ Wchunk,
                                                 float* __restrict__ C,
                                                 const float* __restrict__ bias,
                                                 const float* __restrict__ att,
                                                 ushortT* __restrict__ hout,
                                                 int in_dim, int nseg, int mode) {
  __shared__ ushortT As[2][128 * 64];
  __shared__ float sm[128][4];
  const int tid = threadIdx.x;
  const int bm = blockIdx.x * 128;
  const int wv = tid >> 6, l = tid & 63;
  const int wr = wv >> 2, wc = wv & 3;
  const int lm = l & 15, lq = l >> 4;
  const int nkt = in_dim >> 6;
  const int first = (mode == 0) ? 1 : 0;
  const int totKt = nseg * nkt;

  f32x4 acc[4][4];
#pragma unroll
  for (int mt = 0; mt < 4; mt++)
#pragma unroll
    for (int nt = 0; nt < 4; nt++) acc[mt][nt] = (f32x4){0.f, 0.f, 0.f, 0.f};

  auto stage = [&](int buf, int seg, int kt) {
    const ushortT* ab; size_t str;
    if (first && seg == 0) { ab = xin; str = (size_t)in_dim; }
    else { ab = aggB + (size_t)(seg - first) * in_dim; str = (size_t)4 * in_dim; }
#pragma unroll
    for (int j = 0; j < 2; j++) {
      int r = wv * 16 + j * 8;                 // wave-uniform LDS row base
      int g = bm + r + (l >> 3); if (g >= NN) g = NN - 1;
      const ushortT* gp = ab + (size_t)g * str + kt * 64 + (l & 7) * 8;
      ushortT* lp = &As[buf][r * 64];
      __builtin_amdgcn_global_load_lds((glb_void*)gp, (lds_void*)lp, 16, 0, 0);
    }
  };

  auto mfmaTile = [&](int buf, int segC, int ktC) {
    short8 bf[2][4];
    const ushortT* wt = Wchunk + (size_t)(wc * 64 + lm) * in_dim +
                        (size_t)segC * 256 * in_dim + ktC * 64 + lq * 8;
#pragma unroll
    for (int nt = 0; nt < 4; nt++) {
      bf[0][nt] = *(const short8*)(wt + (size_t)nt * 16 * in_dim);
      bf[1][nt] = *(const short8*)(wt + (size_t)nt * 16 * in_dim + 32);
    }
#pragma unroll
    for (int ks = 0; ks < 2; ks++) {
      short8 af[4];
#pragma unroll
      for (int mt = 0; mt < 4; mt++) {
        int ar = wr * 64 + mt * 16 + lm;
        af[mt] = *(const short8*)(&As[buf][ar * 64 + (((ks * 4) + lq) ^ (ar & 7)) * 8]);
      }
#pragma unroll
      for (int mt = 0; mt < 4; mt++)
#pragma unroll
        for (int nt = 0; nt < 4; nt++)
          acc[mt][nt] = __builtin_amdgcn_mfma_f32_16x16x32_bf16(af[mt], bf[ks][nt],
                                                                acc[mt][nt], 0, 0, 0);
    }
  };

  int segL = 0, ktL = 0, segP = 0, ktP = 0;
  auto bump = [&](int& s, int& k) { if (++k == nkt) { k = 0; s++; } };

  stage(0, 0, 0);
  __syncthreads();
  for (int t = 0; t < totKt; t++) {
    if (t + 1 < totKt) { bump(segP, ktP); stage((t + 1) & 1, segP, ktP); }
    mfmaTile(t & 1, segL, ktL);
    bump(segL, ktL);
    __syncthreads();
  }

  if (mode == 2) {
    // fold in prior chunks' C, fused head-softmax attention, swizzled bf16 store
#pragma unroll
    for (int mt = 0; mt < 4; mt++)
#pragma unroll
      for (int r = 0; r < 4; r++) {
        int row = bm + wr * 64 + mt * 16 + lq * 4 + r;
        if (row < NN) {
          const float* cp = C + (size_t)row * HDIM + wc * 64;
#pragma unroll
          for (int nt = 0; nt < 4; nt++) acc[mt][nt][r] += cp[nt * 16 + lm];
        }
      }
    float av[4];
#pragma unroll
    for (int nt = 0; nt < 4; nt++) av[nt] = att[wc * 64 + nt * 16 + lm];
#pragma unroll
    for (int mt = 0; mt < 4; mt++) {
      float sr[4];
#pragma unroll
      for (int r = 0; r < 4; r++)
        sr[r] = acc[mt][0][r] * av[0] + acc[mt][1][r] * av[1] +
                acc[mt][2][r] * av[2] + acc[mt][3][r] * av[3];
#pragma unroll
      for (int o = 1; o <= 8; o <<= 1) {
#pragma unroll
        for (int r = 0; r < 4; r++) sr[r] += __shfl_xor(sr[r], o, 64);
      }
      if (lm == 0) {
#pragma unroll
        for (int r = 0; r < 4; r++) sm[wr * 64 + mt * 16 + lq * 4 + r][wc] = sr[r];
      }
    }
    __syncthreads();
    if (tid < 128) {
      float s0 = sm[tid][0], s1 = sm[tid][1], s2 = sm[tid][2], s3 = sm[tid][3];
      float mx = fmaxf(fmaxf(s0, s1), fmaxf(s2, s3));
      float e0 = __expf(s0 - mx), e1 = __expf(s1 - mx), e2 = __expf(s2 - mx), e3 = __expf(s3 - mx);
      float inv = 1.0f / (e0 + e1 + e2 + e3);
      sm[tid][0] = e0 * inv; sm[tid][1] = e1 * inv; sm[tid][2] = e2 * inv; sm[tid][3] = e3 * inv;
    }
    __syncthreads();
#pragma unroll
    for (int mt = 0; mt < 4; mt++) {
#pragma unroll
      for (int r = 0; r < 4; r++) {
        int rl = wr * 64 + mt * 16 + lq * 4 + r;
        int row = bm + rl;
        if (row >= NN) continue;
        float al = sm[rl][wc];
        ushortT* op = hout + (size_t)row * HDIM + wc * 64;   // kt-group == head == wc
        int key = row & 7;
#pragma unroll
        for (int nt = 0; nt < 4; nt++) {
          int ci = nt * 16 + lm;
          op[(((ci >> 3) ^ key) * 8) + (ci & 7)] = f2bu(acc[mt][nt][r] * al);
        }
      }
    }
  } else {
    // through-LDS coalesced fp32 C write, 4 slices of 32 rows
    float* Asf = (float*)As;
    for (int s = 0; s < 4; s++) {
      __syncthreads();
      if (wr == (s >> 1)) {
        int mtb = (s & 1) * 2;
#pragma unroll
        for (int mtl = 0; mtl < 2; mtl++)
#pragma unroll
          for (int r = 0; r < 4; r++)
#pragma unroll
            for (int nt = 0; nt < 4; nt++)
              Asf[(mtl * 16 + lq * 4 + r) * 256 + wc * 64 + nt * 16 + lm] =
                  acc[mtb + mtl][nt][r];
      }
      __syncthreads();
#pragma unroll
      for (int j = 0; j < 4; j++) {
        int f = j * 512 + tid;          // float4 index 0..2047
        int row = f >> 6, c4 = (f & 63) * 4;
        int grow = bm + s * 32 + row;
        if (grow < NN) {
          float4 v = *(float4*)(&Asf[row * 256 + c4]);
          float* cp = C + (size_t)grow * HDIM + c4;
          if (mode == 1) {
            float4 o = *(float4*)cp;
            v.x += o.x; v.y += o.y; v.z += o.z; v.w += o.w;
          } else {
            v.x += bias[c4]; v.y += bias[c4 + 1];
            v.z += bias[c4 + 2]; v.w += bias[c4 + 3];
          }
          *(float4*)cp = v;
        }
      }
    }
  }
}

// ---------- prediction head: h is swizzled; un-swizzle on read ----------
__global__ void k_pred(const ushortT* __restrict__ h, const float* __restrict__ w,
                       const float* __restrict__ b, float* __restrict__ out) {
  int t = blockIdx.x * 256 + threadIdx.x;
  if (t >= NN * 12) return;
  int n = t / 12, j = t - n * 12;
  float acc = b[j];
  const ushortT* hp = h + (size_t)n * HDIM;
  int key = n & 7;
#pragma unroll
  for (int kt = 0; kt < 4; kt++)
#pragma unroll
    for (int cs = 0; cs < 8; cs++) {
      int ch = cs ^ key;                 // logical chunk for stored chunk cs
      int kb = kt * 64 + ch * 8;
      const ushortT* hh = hp + kt * 64 + cs * 8;
#pragma unroll
      for (int o = 0; o < 8; o++) acc += bu2f(hh[o]) * w[(kb + o) * 12 + j];
    }
  out[t] = acc;
}

extern "C" void kernel_launch(void* const* d_in, const int* in_sizes, int n_in,
                              void* d_out, int out_size, void* d_ws, size_t ws_size,
                              hipStream_t stream) {
  const float* x         = (const float*)d_in[0];
  const int*   edge_idx  = (const int*)d_in[1];
  const int*   edge_type = (const int*)d_in[2];
  const int*   gene_idx  = (const int*)d_in[3];
  const int*   path_idx  = (const int*)d_in[4];
  const float* gene_emb  = (const float*)d_in[5];
  const float* path_emb  = (const float*)d_in[6];
  const float* comp1     = (const float*)d_in[7];
  const float* basis1    = (const float*)d_in[8];
  const float* root1     = (const float*)d_in[9];
  const float* bias1     = (const float*)d_in[10];
  const float* att1      = (const float*)d_in[11];
  const float* comp2     = (const float*)d_in[12];
  const float* basis2    = (const float*)d_in[13];
  const float* root2     = (const float*)d_in[14];
  const float* bias2     = (const float*)d_in[15];
  const float* att2      = (const float*)d_in[16];
  const float* pred_w    = (const float*)d_in[17];
  const float* pred_b    = (const float*)d_in[18];
  float* out = (float*)d_out;

  // workspace layout (bytes, 16B aligned); total ~218 MB (252 MB proven safe)
  char* ws = (char*)d_ws;
  float*   C     = (float*)(ws);                     // 50048*256*4 = 51,249,152
  ushortT* x0b   = (ushortT*)(ws + 51249152);        // 19.2 MB (h2b overlays later)
  ushortT* h2b   = (ushortT*)(ws + 51249152);        // 25.6 MB (x0b dead by then)
  ushortT* h1b   = (ushortT*)(ws + 76849152);        // 25,600,000
  ushortT* aggB  = (ushortT*)(ws + 102449152);       // 50000*4*256*2 = 102,400,000
  ushortT* Wall1 = (ushortT*)(ws + 204849152);       // 13*256*192*2 = 1,277,952
  ushortT* Wall2 = (ushortT*)(ws + 206127104);       // 13*256*256*2 = 1,703,936
  int*     cnt   = (int*)(ws + 207831040);           // 2,400,000
  int*     off   = (int*)(ws + 210231040);           // 2,400,000
  int*     srcs  = (int*)(ws + 212631040);           // 3,200,000
  int*     fill  = (int*)(ws + 215831040);           // 2,400,000
  int*     bsum  = (int*)(ws + 218231040);           // 4 KB
  int*     bscan = (int*)(ws + 218235136);           // 4 KB

  dim3 blk(256);

  // ---- stage 0: features + CSR build + weight prep ----
  k_build_x0<<<dim3((NN * IN1) / 256), blk, 0, stream>>>(x, x0b);
  k_add_emb<<<dim3((NGENE * EMBD) / 256), blk, 0, stream>>>(gene_idx, gene_emb, x0b, NGENE);
  k_add_emb<<<dim3((NPATH * EMBD) / 256), blk, 0, stream>>>(path_idx, path_emb, x0b, NPATH);
  hipMemsetAsync(cnt, 0, NRK * 4, stream);
  hipMemsetAsync(fill, 0, NRK * 4, stream);
  k_count<<<dim3(NE / 256), blk, 0, stream>>>(edge_idx, edge_type, cnt);
  k_scan1<<<dim3(NSB), blk, 0, stream>>>(cnt, bsum);
  k_scan2<<<dim3(1), dim3(1024), 0, stream>>>(bsum, bscan);
  k_scan3<<<dim3(NSB), blk, 0, stream>>>(cnt, bscan, off);
  k_fill<<<dim3(NE / 256), blk, 0, stream>>>(edge_idx, edge_type, off, fill, srcs);
  k_troot<<<dim3((IN1 * HDIM) / 256), blk, 0, stream>>>(root1, Wall1, IN1);
  k_troot<<<dim3((HDIM * HDIM) / 256), blk, 0, stream>>>(root2, Wall2, HDIM);
  k_wcat<<<dim3((RR * HDIM * IN1) / 256), blk, 0, stream>>>(comp1, basis1, Wall1 + 256 * IN1, IN1);
  k_wcat<<<dim3((RR * HDIM * HDIM) / 256), blk, 0, stream>>>(comp2, basis2, Wall2 + 256 * HDIM, HDIM);

  dim3 agrid(NN), gblk(512), ggrid(391);

  // ---- conv1: chunks {root+r0-3}, {r4-7}, {r8-11 + attention} ----
  k_agg<<<agrid, blk, 0, stream>>>(srcs, off, cnt, x0b, aggB, IN1, 0);
  k_gemm<<<ggrid, gblk, 0, stream>>>(x0b, aggB, Wall1, C, bias1, nullptr, nullptr, IN1, 5, 0);
  k_agg<<<agrid, blk, 0, stream>>>(srcs, off, cnt, x0b, aggB, IN1, 4);
  k_gemm<<<ggrid, gblk, 0, stream>>>(x0b, aggB, Wall1 + (size_t)5 * 256 * IN1, C, bias1,
                                     nullptr, nullptr, IN1, 4, 1);
  k_agg<<<agrid, blk, 0, stream>>>(srcs, off, cnt, x0b, aggB, IN1, 8);
  k_gemm<<<ggrid, gblk, 0, stream>>>(x0b, aggB, Wall1 + (size_t)9 * 256 * IN1, C, bias1,
                                     att1, h1b, IN1, 4, 2);

  // ---- conv2 ----
  k_agg<<<agrid, blk, 0, stream>>>(srcs, off, cnt, h1b, aggB, HDIM, 0);
  k_gemm<<<ggrid, gblk, 0, stream>>>(h1b, aggB, Wall2, C, bias2, nullptr, nullptr, HDIM, 5, 0);
  k_agg<<<agrid, blk, 0, stream>>>(srcs, off, cnt, h1b, aggB, HDIM, 4);
  k_gemm<<<ggrid, gblk, 0, stream>>>(h1b, aggB, Wall2 + (size_t)5 * 256 * HDIM, C, bias2,
                                     nullptr, nullptr, HDIM, 4, 1);
  k_agg<<<agrid, blk, 0, stream>>>(srcs, off, cnt, h1b, aggB, HDIM, 8);
  k_gemm<<<ggrid, gblk, 0, stream>>>(h1b, aggB, Wall2 + (size_t)9 * 256 * HDIM, C, bias2,
                                     att2, h2b, HDIM, 4, 2);

  // ---- prediction head ----
  k_pred<<<dim3((NN * 12 + 255) / 256), blk, 0, stream>>>(h2b, pred_w, pred_b, out);
}